// Round 6
// baseline (1648.954 us; speedup 1.0000x reference)
//
#include <hip/hip_runtime.h>

// ============================================================================
// FilteredTensorProduct: out[n,c] = sum_{a,b} x1[n,a] x2[n,b] ww3j[a,b,c]
//   ww3j = sum_p weights[p] * W3J[p]   (23 SO(3) CG paths, lmax=3, dims 16)
//
// v5:
//  - REMOVE nontemporal stores (v4 counter evidence: WRITE_SIZE doubled,
//    126->245 GB*KB -- nt defeats L2 merging of 16B partial-line stores).
//    Plain dwordx4 stores merge to full lines (v1 measured ideal writes).
//  - LDS-staged input loads: global loads are lane-consecutive float4
//    (1KB/instr, dense) instead of 16B-at-stride-64B (which touches 64
//    lines per instr at 25% utilization -- the 2.3TB/s effective ceiling
//    of v1/v4). Rows are read back from LDS padded to 80B stride ->
//    bank-balanced 8-deep ds_read_b128 (inherent minimum, no conflicts).
//  - coefficients: v1-proven per-lane VGPR stripe + readlane broadcast
//    (zero per-row memory traffic, 1 VALU op/entry).
//  - keep v4's pair-grouped flat unrolled schedule (246 muls vs 359) and
//    first-touch accumulator init. Keep plain __launch_bounds__(256):
//    the v2/v3 spill catastrophe was the (256,4) VGPR cap, not SROA.
// ============================================================================

typedef float v4f __attribute__((ext_vector_type(4)));

// ---------------- compile-time sparsity pattern ----------------
struct Tables {
  int npaths;
  int pl1[32], pl2[32], plo[32];
  int nent;
  int pstart[33];
  unsigned char ea[512], eb[512], ec[512], ep[512];
};

constexpr Tables build_tables() {
  Tables t{};
  for (int lo = 0; lo <= 3; ++lo)
    for (int l1 = 0; l1 <= 3; ++l1)
      for (int l2 = 0; l2 <= 3; ++l2) {
        if (((l1 + l2 + lo) & 1) != 0) continue;           // parity rule
        int lmin = l1 > l2 ? l1 - l2 : l2 - l1;
        if (lo > l1 + l2 || lo < lmin) continue;           // triangle rule
        int p = t.npaths;
        t.pl1[p] = l1; t.pl2[p] = l2; t.plo[p] = lo;
        t.pstart[p] = t.nent;
        int o1 = l1 * l1, o2 = l2 * l2, oo = lo * lo;
        for (int m1 = -l1; m1 <= l1; ++m1)
          for (int m2 = -l2; m2 <= l2; ++m2) {
            int cand[2] = {0, 0}; int nc = 0;
            if (m1 == 0) cand[nc++] = m2;                  // Y_{l,0} has no phi dep
            else if (m2 == 0) cand[nc++] = m1;
            else {
              int u = m1 < 0 ? -m1 : m1, v = m2 < 0 ? -m2 : m2;
              int d = u > v ? u - v : v - u;
              if ((m1 > 0) == (m2 > 0)) {                  // cos*cos or sin*sin -> cos
                cand[nc++] = u + v; cand[nc++] = d;
              } else {                                     // sin*cos -> sin
                cand[nc++] = -(u + v);
                if (d) cand[nc++] = -d;                    // sin(0) == 0
              }
            }
            for (int q = 0; q < nc; ++q) {
              int m3 = cand[q];
              int am3 = m3 < 0 ? -m3 : m3;
              if (am3 <= lo) {
                t.ea[t.nent] = (unsigned char)(o1 + l1 + m1);
                t.eb[t.nent] = (unsigned char)(o2 + l2 + m2);
                t.ec[t.nent] = (unsigned char)(oo + lo + m3);
                t.ep[t.nent] = (unsigned char)p;
                ++t.nent;
              }
            }
          }
        ++t.npaths;
        t.pstart[t.npaths] = t.nent;
      }
  return t;
}

constexpr Tables TBL = build_tables();

// -------- flat compile-time schedule, grouped by unique (a,b) pair --------
struct Sched {
  int nent;
  unsigned char sa[512], sb[512], sc[512], sp[512];
  bool newpair[512];                // slot starts a new (a,b) product
  bool firstc[512];                 // slot is globally first touch of its c
};

constexpr Sched build_sched() {
  Sched s{};
  int pos = 0;
  bool seen[16] = {};
  for (int a = 0; a < 16; ++a)
    for (int b = 0; b < 16; ++b) {
      bool first_of_pair = true;
      for (int e = 0; e < TBL.nent; ++e) {
        if ((int)TBL.ea[e] == a && (int)TBL.eb[e] == b) {
          s.sa[pos] = (unsigned char)a;
          s.sb[pos] = (unsigned char)b;
          s.sc[pos] = TBL.ec[e];
          s.sp[pos] = TBL.ep[e];
          s.newpair[pos] = first_of_pair;
          s.firstc[pos] = !seen[TBL.ec[e]];
          seen[TBL.ec[e]] = true;
          first_of_pair = false;
          ++pos;
        }
      }
    }
  s.nent = pos;
  return s;
}

constexpr Sched SCH = build_sched();
constexpr int NENT = SCH.nent;                 // 359
constexpr int NCREG = (NENT + 63) / 64;        // 6 coef VGPRs per lane
static_assert(SCH.nent == TBL.nent, "schedule must cover all entries");
static_assert(SCH.nent <= 512, "table overflow");

// ---------------- device CG math (fp64, transcribes reference) -------------
__device__ __constant__ double FACT[11] = {
    1., 1., 2., 6., 24., 120., 720., 5040., 40320., 362880., 3628800.};

struct cplx { double re, im; };

__device__ inline double su2_cg(int j1, int m1, int j2, int m2, int j3, int m3) {
  if (m3 != m1 + m2) return 0.0;
  int vmin = -j1 + j2 + m3;
  if (-j1 + m1 > vmin) vmin = -j1 + m1;
  if (0 > vmin) vmin = 0;
  int vmax = j2 + j3 + m1;
  if (j3 - j1 + j2 < vmax) vmax = j3 - j1 + j2;
  if (j3 + m3 < vmax) vmax = j3 + m3;
  double C = (2.0 * j3 + 1.0) *
             (FACT[j3 + j1 - j2] * FACT[j3 - j1 + j2] * FACT[j1 + j2 - j3] *
              FACT[j3 + m3] * FACT[j3 - m3]) /
             (FACT[j1 + j2 + j3 + 1] * FACT[j1 - m1] * FACT[j1 + m1] *
              FACT[j2 - m2] * FACT[j2 + m2]);
  double S = 0.0;
  for (int v = vmin; v <= vmax; ++v) {
    double t = (FACT[j2 + j3 + m1 - v] * FACT[j1 - m1 + v]) /
               (FACT[v] * FACT[j3 - j1 + j2 - v] * FACT[j3 + m3 - v] *
                FACT[v + j1 - j2 - m3]);
    S += (((v + j2 + m2) & 1) ? -1.0 : 1.0) * t;
  }
  return sqrt(C) * S;
}

// q[l+m, l+-|m|] of _change_basis_real_to_complex, incl. global (-i)^l phase.
__device__ inline cplx Qmat(int l, int r, int c) {
  int m = r - l, mc = c - l;
  const double is2 = 0.70710678118654752440;
  double re = 0.0, im = 0.0;
  if (m < 0) {
    if (mc == -m) re = is2;
    else if (mc == m) im = -is2;
  } else if (m == 0) {
    if (mc == 0) re = 1.0;
  } else {
    double s = (m & 1) ? -is2 : is2;
    if (mc == m) re = s;
    else if (mc == -m) im = s;
  }
  cplx out;
  switch (l & 3) {                   // multiply by (-i)^l
    case 0: out.re = re;  out.im = im;  break;
    case 1: out.re = im;  out.im = -re; break;
    case 2: out.re = -re; out.im = -im; break;
    default: out.re = -im; out.im = re; break;
  }
  return out;
}

// One block per path. Computes real-basis CG values and writes
// weights[p]*sqrt(2lo+1)*Creal into the SCHEDULE-ORDERED coefficient slots.
__global__ void cg_setup_kernel(const float* __restrict__ weights,
                                float* __restrict__ wwc) {
  const int p = blockIdx.x;
  const int l1 = TBL.pl1[p], l2 = TBL.pl2[p], lo = TBL.plo[p];
  const int n1 = 2 * l1 + 1, n2 = 2 * l2 + 1, n3 = 2 * lo + 1;
  const int tot = n1 * n2 * n3;
  const int tid = (int)threadIdx.x;
  const int bd = (int)blockDim.x;

  __shared__ double Cs[343];
  __shared__ double Vr[343], Vi[343];
  __shared__ double Ur[343], Ui[343];
  __shared__ double Rr[343];

  // stage 0: SU(2) CG tensor Cs[i,k,n]
  for (int idx = tid; idx < tot; idx += bd) {
    int i = idx / (n2 * n3), r = idx % (n2 * n3);
    int k = r / n3, nn = r % n3;
    Cs[idx] = su2_cg(l1, i - l1, l2, k - l2, lo, nn - lo);
  }
  __syncthreads();

  // stage A: V[i,k,m] = sum_n Cs[i,k,n] * conj(Q3[n,m])
  for (int idx = tid; idx < tot; idx += bd) {
    int i = idx / (n2 * n3), r = idx % (n2 * n3);
    int k = r / n3, m = r % n3;
    double vr = 0.0, vi = 0.0;
    for (int nn = 0; nn < n3; ++nn) {
      double c = Cs[(i * n2 + k) * n3 + nn];
      cplx q = Qmat(lo, nn, m);
      vr += c * q.re;
      vi -= c * q.im;
    }
    Vr[idx] = vr; Vi[idx] = vi;
  }
  __syncthreads();

  // stage B: U[i,l,m] = sum_k Q2[k,l] * V[i,k,m]
  for (int idx = tid; idx < tot; idx += bd) {
    int i = idx / (n2 * n3), r = idx % (n2 * n3);
    int l = r / n3, m = r % n3;
    double ur = 0.0, ui = 0.0;
    for (int k = 0; k < n2; ++k) {
      cplx q = Qmat(l2, k, l);
      double vr = Vr[(i * n2 + k) * n3 + m];
      double vi = Vi[(i * n2 + k) * n3 + m];
      ur += q.re * vr - q.im * vi;
      ui += q.re * vi + q.im * vr;
    }
    Ur[idx] = ur; Ui[idx] = ui;
  }
  __syncthreads();

  // stage C: R[j,l,m] = Re( sum_i Q1[i,j] * U[i,l,m] )
  for (int idx = tid; idx < tot; idx += bd) {
    int j = idx / (n2 * n3), r = idx % (n2 * n3);
    int l = r / n3, m = r % n3;
    double rr = 0.0;
    for (int i = 0; i < n1; ++i) {
      cplx q = Qmat(l1, i, j);
      rr += q.re * Ur[(i * n2 + l) * n3 + m] - q.im * Ui[(i * n2 + l) * n3 + m];
    }
    Rr[idx] = rr;
  }
  __syncthreads();

  // write schedule-ordered coefficients belonging to this path
  const double wsc = (double)weights[p] * sqrt(2.0 * lo + 1.0);
  const int o1 = l1 * l1, o2 = l2 * l2, oo = lo * lo;
  for (int s = tid; s < NENT; s += bd) {
    if ((int)SCH.sp[s] != p) continue;
    int i = (int)SCH.sa[s] - o1;
    int j = (int)SCH.sb[s] - o2;
    int k = (int)SCH.sc[s] - oo;
    wwc[s] = (float)(wsc * Rr[(i * n2 + j) * n3 + k]);
  }
}

// ---------------- main contraction kernel ----------------
// Block stages 256 rows of x1/x2 through LDS with DENSE global loads;
// each thread then owns one row read back from padded LDS.
constexpr int ROWSTRIDE = 20;   // dwords: 16 data + 4 pad -> 80B, bank-balanced

__global__ __launch_bounds__(256) void tp_kernel(const float* __restrict__ x1,
                                                 const float* __restrict__ x2,
                                                 const float* __restrict__ wwc,
                                                 float* __restrict__ out,
                                                 int n) {
  __shared__ float lsh[2 * 256 * ROWSTRIDE];   // 40 KB

  const int t = (int)threadIdx.x;
  const int blockRow = (int)blockIdx.x * 256;
  const int nrows = n - blockRow;              // >=1 by grid construction
  const int maxf = nrows < 256 ? nrows * 4 : 1024;  // valid float4s this block

  // coefficient stripe: lane L holds wwc[L + 64k]; loaded while LDS fills
  float creg[NCREG];
#pragma unroll
  for (int k = 0; k < NCREG; ++k) creg[k] = wwc[k * 64 + (t & 63)];

  // dense, fully-coalesced staging loads (1 KB per wave-instruction)
  const v4f* G1 = reinterpret_cast<const v4f*>(x1) + (size_t)blockRow * 4;
  const v4f* G2 = reinterpret_cast<const v4f*>(x2) + (size_t)blockRow * 4;
#pragma unroll
  for (int q = 0; q < 4; ++q) {
    int f = q * 256 + t;                       // float4 index within block
    int fc = f < maxf ? f : maxf - 1;          // tail clamp (loads stay valid)
    int r = fc >> 2, c = fc & 3;
    v4f v = G1[fc];
    *reinterpret_cast<v4f*>(&lsh[r * ROWSTRIDE + c * 4]) = v;
    v4f u = G2[fc];
    *reinterpret_cast<v4f*>(&lsh[256 * ROWSTRIDE + r * ROWSTRIDE + c * 4]) = u;
  }
  __syncthreads();

  // read own row from LDS (80B stride: 8-deep bank-balanced b128 reads)
  float a[16], b[16];
#pragma unroll
  for (int c = 0; c < 4; ++c) {
    v4f va = *reinterpret_cast<const v4f*>(&lsh[t * ROWSTRIDE + c * 4]);
    a[4 * c + 0] = va.x; a[4 * c + 1] = va.y;
    a[4 * c + 2] = va.z; a[4 * c + 3] = va.w;
    v4f vb = *reinterpret_cast<const v4f*>(
        &lsh[256 * ROWSTRIDE + t * ROWSTRIDE + c * 4]);
    b[4 * c + 0] = vb.x; b[4 * c + 1] = vb.y;
    b[4 * c + 2] = vb.z; b[4 * c + 3] = vb.w;
  }

  float acc[16];                     // first-touch initialized via firstc
  float tprod = 0.0f;                // current (a,b) product

#pragma unroll
  for (int e = 0; e < NENT; ++e) {
    // all SCH.* reads constant-fold after full unroll (proven pattern)
    if (SCH.newpair[e]) tprod = a[SCH.sa[e]] * b[SCH.sb[e]];
    // wave-uniform coefficient -> SGPR via readlane (compile-time lane idx)
    int wb = __builtin_amdgcn_readlane(__float_as_int(creg[e >> 6]), e & 63);
    float w = __int_as_float(wb);
    if (SCH.firstc[e]) acc[SCH.sc[e]] = w * tprod;
    else               acc[SCH.sc[e]] = fmaf(w, tprod, acc[SCH.sc[e]]);
  }

  const int row = blockRow + t;
  if (row < n) {
    v4f* O = reinterpret_cast<v4f*>(out) + (size_t)row * 4;
#pragma unroll
    for (int q = 0; q < 4; ++q) {
      v4f o;
      o.x = acc[4 * q + 0]; o.y = acc[4 * q + 1];
      o.z = acc[4 * q + 2]; o.w = acc[4 * q + 3];
      O[q] = o;                                 // plain store: L2 merges lines
    }
  }
}

// ---------------- launch ----------------
extern "C" void kernel_launch(void* const* d_in, const int* in_sizes, int n_in,
                              void* d_out, int out_size, void* d_ws,
                              size_t ws_size, hipStream_t stream) {
  const float* x1 = (const float*)d_in[0];
  const float* x2 = (const float*)d_in[1];
  const float* w  = (const float*)d_in[2];
  float* out = (float*)d_out;
  float* wwc = (float*)d_ws;   // NENT compacted coefficients (schedule order)

  const int n = in_sizes[0] / 16;

  // 1) compute compacted ww3j coefficients (23 tiny blocks)
  cg_setup_kernel<<<dim3(TBL.npaths), dim3(256), 0, stream>>>(w, wwc);

  // 2) LDS-staged per-row contraction
  const int grid = (n + 255) / 256;
  tp_kernel<<<dim3(grid), dim3(256), 0, stream>>>(x1, x2, wwc, out, n);
}

// Round 7
// 1513.842 us; speedup vs baseline: 1.0893x; 1.0893x over previous
//
#include <hip/hip_runtime.h>

// ============================================================================
// FilteredTensorProduct: out[n,c] = sum_{a,b} x1[n,a] x2[n,b] ww3j[a,b,c]
//   ww3j = sum_p weights[p] * W3J[p]   (23 SO(3) CG paths, lmax=3, dims 16)
//
// v6: v1-proven skeleton + 2 rows/thread, assembled strictly from pieces
// that have been individually validated on hardware:
//  - direct strided float4 global loads (v1: ideal FETCH, L1 captures the
//    4-line transient) -- NO LDS staging (v5: compiler folds the row copy
//    back into per-use ds_reads, 8-way bank conflicts, 1521us).
//  - readlane coefficient stripe (v1: 1 VALU op/entry, zero traffic) --
//    NOT per-entry wwc[e] loads (v4: +25us VMEM issue pressure).
//  - plain stores (v1/v5: L2 merges 16B partials to ideal WRITE) -- NOT
//    nontemporal (v4: WRITE_SIZE doubled).
//  - flat #pragma unroll schedule with constexpr newpair/firstc flags
//    (v4: constant-folds, promotes, 72 VGPR): 246 muls instead of 359,
//    first-touch acc init.
//  - 2 rows/thread (r0=bid*512+t, r1=r0+256): 16 outstanding loads/thread
//    to attack the measured latency-bound regime (v1: 28% HBM, 43% VALU,
//    8 waves/CU). Plain __launch_bounds__(256): the v2/v3 scratch
//    catastrophe was the (256,4) 128-VGPR cap, not SROA -- 96 floats need
//    ~150 VGPR and must not be capped.
// ============================================================================

typedef float v4f __attribute__((ext_vector_type(4)));

// ---------------- compile-time sparsity pattern ----------------
struct Tables {
  int npaths;
  int pl1[32], pl2[32], plo[32];
  int nent;
  int pstart[33];
  unsigned char ea[512], eb[512], ec[512], ep[512];
};

constexpr Tables build_tables() {
  Tables t{};
  for (int lo = 0; lo <= 3; ++lo)
    for (int l1 = 0; l1 <= 3; ++l1)
      for (int l2 = 0; l2 <= 3; ++l2) {
        if (((l1 + l2 + lo) & 1) != 0) continue;           // parity rule
        int lmin = l1 > l2 ? l1 - l2 : l2 - l1;
        if (lo > l1 + l2 || lo < lmin) continue;           // triangle rule
        int p = t.npaths;
        t.pl1[p] = l1; t.pl2[p] = l2; t.plo[p] = lo;
        t.pstart[p] = t.nent;
        int o1 = l1 * l1, o2 = l2 * l2, oo = lo * lo;
        for (int m1 = -l1; m1 <= l1; ++m1)
          for (int m2 = -l2; m2 <= l2; ++m2) {
            int cand[2] = {0, 0}; int nc = 0;
            if (m1 == 0) cand[nc++] = m2;                  // Y_{l,0} has no phi dep
            else if (m2 == 0) cand[nc++] = m1;
            else {
              int u = m1 < 0 ? -m1 : m1, v = m2 < 0 ? -m2 : m2;
              int d = u > v ? u - v : v - u;
              if ((m1 > 0) == (m2 > 0)) {                  // cos*cos or sin*sin -> cos
                cand[nc++] = u + v; cand[nc++] = d;
              } else {                                     // sin*cos -> sin
                cand[nc++] = -(u + v);
                if (d) cand[nc++] = -d;                    // sin(0) == 0
              }
            }
            for (int q = 0; q < nc; ++q) {
              int m3 = cand[q];
              int am3 = m3 < 0 ? -m3 : m3;
              if (am3 <= lo) {
                t.ea[t.nent] = (unsigned char)(o1 + l1 + m1);
                t.eb[t.nent] = (unsigned char)(o2 + l2 + m2);
                t.ec[t.nent] = (unsigned char)(oo + lo + m3);
                t.ep[t.nent] = (unsigned char)p;
                ++t.nent;
              }
            }
          }
        ++t.npaths;
        t.pstart[t.npaths] = t.nent;
      }
  return t;
}

constexpr Tables TBL = build_tables();

// -------- flat compile-time schedule, grouped by unique (a,b) pair --------
struct Sched {
  int nent;
  unsigned char sa[512], sb[512], sc[512], sp[512];
  bool newpair[512];                // slot starts a new (a,b) product
  bool firstc[512];                 // slot is globally first touch of its c
};

constexpr Sched build_sched() {
  Sched s{};
  int pos = 0;
  bool seen[16] = {};
  for (int a = 0; a < 16; ++a)
    for (int b = 0; b < 16; ++b) {
      bool first_of_pair = true;
      for (int e = 0; e < TBL.nent; ++e) {
        if ((int)TBL.ea[e] == a && (int)TBL.eb[e] == b) {
          s.sa[pos] = (unsigned char)a;
          s.sb[pos] = (unsigned char)b;
          s.sc[pos] = TBL.ec[e];
          s.sp[pos] = TBL.ep[e];
          s.newpair[pos] = first_of_pair;
          s.firstc[pos] = !seen[TBL.ec[e]];
          seen[TBL.ec[e]] = true;
          first_of_pair = false;
          ++pos;
        }
      }
    }
  s.nent = pos;
  return s;
}

constexpr Sched SCH = build_sched();
constexpr int NENT = SCH.nent;                 // 359
constexpr int NCREG = (NENT + 63) / 64;        // 6 coef VGPRs per lane
static_assert(SCH.nent == TBL.nent, "schedule must cover all entries");
static_assert(SCH.nent <= 512, "table overflow");

// ---------------- device CG math (fp64, transcribes reference) -------------
__device__ __constant__ double FACT[11] = {
    1., 1., 2., 6., 24., 120., 720., 5040., 40320., 362880., 3628800.};

struct cplx { double re, im; };

__device__ inline double su2_cg(int j1, int m1, int j2, int m2, int j3, int m3) {
  if (m3 != m1 + m2) return 0.0;
  int vmin = -j1 + j2 + m3;
  if (-j1 + m1 > vmin) vmin = -j1 + m1;
  if (0 > vmin) vmin = 0;
  int vmax = j2 + j3 + m1;
  if (j3 - j1 + j2 < vmax) vmax = j3 - j1 + j2;
  if (j3 + m3 < vmax) vmax = j3 + m3;
  double C = (2.0 * j3 + 1.0) *
             (FACT[j3 + j1 - j2] * FACT[j3 - j1 + j2] * FACT[j1 + j2 - j3] *
              FACT[j3 + m3] * FACT[j3 - m3]) /
             (FACT[j1 + j2 + j3 + 1] * FACT[j1 - m1] * FACT[j1 + m1] *
              FACT[j2 - m2] * FACT[j2 + m2]);
  double S = 0.0;
  for (int v = vmin; v <= vmax; ++v) {
    double t = (FACT[j2 + j3 + m1 - v] * FACT[j1 - m1 + v]) /
               (FACT[v] * FACT[j3 - j1 + j2 - v] * FACT[j3 + m3 - v] *
                FACT[v + j1 - j2 - m3]);
    S += (((v + j2 + m2) & 1) ? -1.0 : 1.0) * t;
  }
  return sqrt(C) * S;
}

// q[l+m, l+-|m|] of _change_basis_real_to_complex, incl. global (-i)^l phase.
__device__ inline cplx Qmat(int l, int r, int c) {
  int m = r - l, mc = c - l;
  const double is2 = 0.70710678118654752440;
  double re = 0.0, im = 0.0;
  if (m < 0) {
    if (mc == -m) re = is2;
    else if (mc == m) im = -is2;
  } else if (m == 0) {
    if (mc == 0) re = 1.0;
  } else {
    double s = (m & 1) ? -is2 : is2;
    if (mc == m) re = s;
    else if (mc == -m) im = s;
  }
  cplx out;
  switch (l & 3) {                   // multiply by (-i)^l
    case 0: out.re = re;  out.im = im;  break;
    case 1: out.re = im;  out.im = -re; break;
    case 2: out.re = -re; out.im = -im; break;
    default: out.re = -im; out.im = re; break;
  }
  return out;
}

// One block per path. Computes real-basis CG values and writes
// weights[p]*sqrt(2lo+1)*Creal into the SCHEDULE-ORDERED coefficient slots.
__global__ void cg_setup_kernel(const float* __restrict__ weights,
                                float* __restrict__ wwc) {
  const int p = blockIdx.x;
  const int l1 = TBL.pl1[p], l2 = TBL.pl2[p], lo = TBL.plo[p];
  const int n1 = 2 * l1 + 1, n2 = 2 * l2 + 1, n3 = 2 * lo + 1;
  const int tot = n1 * n2 * n3;
  const int tid = (int)threadIdx.x;
  const int bd = (int)blockDim.x;

  __shared__ double Cs[343];
  __shared__ double Vr[343], Vi[343];
  __shared__ double Ur[343], Ui[343];
  __shared__ double Rr[343];

  // stage 0: SU(2) CG tensor Cs[i,k,n]
  for (int idx = tid; idx < tot; idx += bd) {
    int i = idx / (n2 * n3), r = idx % (n2 * n3);
    int k = r / n3, nn = r % n3;
    Cs[idx] = su2_cg(l1, i - l1, l2, k - l2, lo, nn - lo);
  }
  __syncthreads();

  // stage A: V[i,k,m] = sum_n Cs[i,k,n] * conj(Q3[n,m])
  for (int idx = tid; idx < tot; idx += bd) {
    int i = idx / (n2 * n3), r = idx % (n2 * n3);
    int k = r / n3, m = r % n3;
    double vr = 0.0, vi = 0.0;
    for (int nn = 0; nn < n3; ++nn) {
      double c = Cs[(i * n2 + k) * n3 + nn];
      cplx q = Qmat(lo, nn, m);
      vr += c * q.re;
      vi -= c * q.im;
    }
    Vr[idx] = vr; Vi[idx] = vi;
  }
  __syncthreads();

  // stage B: U[i,l,m] = sum_k Q2[k,l] * V[i,k,m]
  for (int idx = tid; idx < tot; idx += bd) {
    int i = idx / (n2 * n3), r = idx % (n2 * n3);
    int l = r / n3, m = r % n3;
    double ur = 0.0, ui = 0.0;
    for (int k = 0; k < n2; ++k) {
      cplx q = Qmat(l2, k, l);
      double vr = Vr[(i * n2 + k) * n3 + m];
      double vi = Vi[(i * n2 + k) * n3 + m];
      ur += q.re * vr - q.im * vi;
      ui += q.re * vi + q.im * vr;
    }
    Ur[idx] = ur; Ui[idx] = ui;
  }
  __syncthreads();

  // stage C: R[j,l,m] = Re( sum_i Q1[i,j] * U[i,l,m] )
  for (int idx = tid; idx < tot; idx += bd) {
    int j = idx / (n2 * n3), r = idx % (n2 * n3);
    int l = r / n3, m = r % n3;
    double rr = 0.0;
    for (int i = 0; i < n1; ++i) {
      cplx q = Qmat(l1, i, j);
      rr += q.re * Ur[(i * n2 + l) * n3 + m] - q.im * Ui[(i * n2 + l) * n3 + m];
    }
    Rr[idx] = rr;
  }
  __syncthreads();

  // write schedule-ordered coefficients belonging to this path
  const double wsc = (double)weights[p] * sqrt(2.0 * lo + 1.0);
  const int o1 = l1 * l1, o2 = l2 * l2, oo = lo * lo;
  for (int s = tid; s < NENT; s += bd) {
    if ((int)SCH.sp[s] != p) continue;
    int i = (int)SCH.sa[s] - o1;
    int j = (int)SCH.sb[s] - o2;
    int k = (int)SCH.sc[s] - oo;
    wwc[s] = (float)(wsc * Rr[(i * n2 + j) * n3 + k]);
  }
}

// ---------------- main contraction kernel ----------------
// 2 rows per thread: r0 = bid*512 + t, r1 = r0 + 256. Both rows' waves
// cover 64 consecutive rows per load instruction (same pattern as v1).
__global__ __launch_bounds__(256) void tp_kernel(const float* __restrict__ x1,
                                                 const float* __restrict__ x2,
                                                 const float* __restrict__ wwc,
                                                 float* __restrict__ out,
                                                 int n) {
  const int t = (int)threadIdx.x;

  // coefficient stripe: lane L holds wwc[L + 64k]. Loaded before any
  // divergence so every lane's VGPRs are valid for readlane.
  float creg[NCREG];
#pragma unroll
  for (int k = 0; k < NCREG; ++k) creg[k] = wwc[k * 64 + (t & 63)];

  const int r0 = (int)blockIdx.x * 512 + t;
  if (r0 >= n) return;
  const int r1 = r0 + 256;
  const bool h1 = (r1 < n);
  const int r1a = h1 ? r1 : r0;          // clamp: loads valid, store guarded

  const v4f* X1a = reinterpret_cast<const v4f*>(x1) + (size_t)r0 * 4;
  const v4f* X2a = reinterpret_cast<const v4f*>(x2) + (size_t)r0 * 4;
  const v4f* X1b = reinterpret_cast<const v4f*>(x1) + (size_t)r1a * 4;
  const v4f* X2b = reinterpret_cast<const v4f*>(x2) + (size_t)r1a * 4;

  float a0[16], b0[16], a1[16], b1[16];
#pragma unroll
  for (int q = 0; q < 4; ++q) {
    v4f v0 = X1a[q];
    a0[4 * q + 0] = v0.x; a0[4 * q + 1] = v0.y;
    a0[4 * q + 2] = v0.z; a0[4 * q + 3] = v0.w;
    v4f u0 = X2a[q];
    b0[4 * q + 0] = u0.x; b0[4 * q + 1] = u0.y;
    b0[4 * q + 2] = u0.z; b0[4 * q + 3] = u0.w;
    v4f v1 = X1b[q];
    a1[4 * q + 0] = v1.x; a1[4 * q + 1] = v1.y;
    a1[4 * q + 2] = v1.z; a1[4 * q + 3] = v1.w;
    v4f u1 = X2b[q];
    b1[4 * q + 0] = u1.x; b1[4 * q + 1] = u1.y;
    b1[4 * q + 2] = u1.z; b1[4 * q + 3] = u1.w;
  }

  float acc0[16], acc1[16];   // first-touch initialized via firstc
  float t0 = 0.0f, t1 = 0.0f; // current (a,b) products

#pragma unroll
  for (int e = 0; e < NENT; ++e) {
    // all SCH.* reads constant-fold after full unroll (v1/v4-proven pattern)
    if (SCH.newpair[e]) {
      t0 = a0[SCH.sa[e]] * b0[SCH.sb[e]];
      t1 = a1[SCH.sa[e]] * b1[SCH.sb[e]];
    }
    // wave-uniform coefficient -> SGPR via readlane (compile-time lane idx);
    // one broadcast feeds both rows' FMAs.
    int wb = __builtin_amdgcn_readlane(__float_as_int(creg[e >> 6]), e & 63);
    float w = __int_as_float(wb);
    if (SCH.firstc[e]) {
      acc0[SCH.sc[e]] = w * t0;
      acc1[SCH.sc[e]] = w * t1;
    } else {
      acc0[SCH.sc[e]] = fmaf(w, t0, acc0[SCH.sc[e]]);
      acc1[SCH.sc[e]] = fmaf(w, t1, acc1[SCH.sc[e]]);
    }
  }

  v4f* O0 = reinterpret_cast<v4f*>(out) + (size_t)r0 * 4;
#pragma unroll
  for (int q = 0; q < 4; ++q) {
    v4f o;
    o.x = acc0[4 * q + 0]; o.y = acc0[4 * q + 1];
    o.z = acc0[4 * q + 2]; o.w = acc0[4 * q + 3];
    O0[q] = o;                                 // plain store: L2 merges lines
  }
  if (h1) {
    v4f* O1 = reinterpret_cast<v4f*>(out) + (size_t)r1 * 4;
#pragma unroll
    for (int q = 0; q < 4; ++q) {
      v4f o;
      o.x = acc1[4 * q + 0]; o.y = acc1[4 * q + 1];
      o.z = acc1[4 * q + 2]; o.w = acc1[4 * q + 3];
      O1[q] = o;
    }
  }
}

// ---------------- launch ----------------
extern "C" void kernel_launch(void* const* d_in, const int* in_sizes, int n_in,
                              void* d_out, int out_size, void* d_ws,
                              size_t ws_size, hipStream_t stream) {
  const float* x1 = (const float*)d_in[0];
  const float* x2 = (const float*)d_in[1];
  const float* w  = (const float*)d_in[2];
  float* out = (float*)d_out;
  float* wwc = (float*)d_ws;   // NENT compacted coefficients (schedule order)

  const int n = in_sizes[0] / 16;

  // 1) compute compacted ww3j coefficients (23 tiny blocks)
  cg_setup_kernel<<<dim3(TBL.npaths), dim3(256), 0, stream>>>(w, wwc);

  // 2) sparse per-row contraction, 2 rows/thread
  const int grid = (n + 511) / 512;
  tp_kernel<<<dim3(grid), dim3(256), 0, stream>>>(x1, x2, wwc, out, n);
}

// Round 8
// 1365.699 us; speedup vs baseline: 1.2074x; 1.1085x over previous
//
#include <hip/hip_runtime.h>

// ============================================================================
// FilteredTensorProduct: out[n,c] = sum_{a,b} x1[n,a] x2[n,b] ww3j[a,b,c]
//   ww3j = sum_p weights[p] * W3J[p]   (23 SO(3) CG paths, lmax=3, dims 16)
//
// v7 = the only register-promotable shape this backend accepts (1 row/thread,
// 3 arrays, flat fully-unrolled loop -- v1: 80 VGPR / 113us; v4: 72 VGPR,
// ideal traffic) + the VALU diet proven to constant-fold in that shape (v4):
//  - pair-grouped schedule: 246 muls instead of 359 (product reused across
//    all c of an (a,b) pair), constexpr newpair flags.
//  - first-touch accumulator init via constexpr firstc flags (no 16 movs).
//  - readlane coefficient stripe (v1-proven): lane L holds wwc[L+64k],
//    broadcast per entry at compile-time lane index. 1 VALU op/entry,
//    zero per-row memory traffic. NOT per-entry wwc[e] loads (v4 cost).
//  - plain dwordx4 stores (L2 merges partial lines; nt stores doubled
//    WRITE_SIZE in v4).
// Dead ends measured and abandoned: 2 rows/thread in any form (v2/v3/v6:
// backend demotes past ~50-60 live floats -> scratch dependency chains,
// 1.4-1.6ms), LDS input staging (v5: copy folded into per-use ds_reads,
// 8-way bank conflicts, 1521us), nt stores (v4), per-entry coef loads (v4).
// ============================================================================

typedef float v4f __attribute__((ext_vector_type(4)));

// ---------------- compile-time sparsity pattern ----------------
struct Tables {
  int npaths;
  int pl1[32], pl2[32], plo[32];
  int nent;
  int pstart[33];
  unsigned char ea[512], eb[512], ec[512], ep[512];
};

constexpr Tables build_tables() {
  Tables t{};
  for (int lo = 0; lo <= 3; ++lo)
    for (int l1 = 0; l1 <= 3; ++l1)
      for (int l2 = 0; l2 <= 3; ++l2) {
        if (((l1 + l2 + lo) & 1) != 0) continue;           // parity rule
        int lmin = l1 > l2 ? l1 - l2 : l2 - l1;
        if (lo > l1 + l2 || lo < lmin) continue;           // triangle rule
        int p = t.npaths;
        t.pl1[p] = l1; t.pl2[p] = l2; t.plo[p] = lo;
        t.pstart[p] = t.nent;
        int o1 = l1 * l1, o2 = l2 * l2, oo = lo * lo;
        for (int m1 = -l1; m1 <= l1; ++m1)
          for (int m2 = -l2; m2 <= l2; ++m2) {
            int cand[2] = {0, 0}; int nc = 0;
            if (m1 == 0) cand[nc++] = m2;                  // Y_{l,0} has no phi dep
            else if (m2 == 0) cand[nc++] = m1;
            else {
              int u = m1 < 0 ? -m1 : m1, v = m2 < 0 ? -m2 : m2;
              int d = u > v ? u - v : v - u;
              if ((m1 > 0) == (m2 > 0)) {                  // cos*cos or sin*sin -> cos
                cand[nc++] = u + v; cand[nc++] = d;
              } else {                                     // sin*cos -> sin
                cand[nc++] = -(u + v);
                if (d) cand[nc++] = -d;                    // sin(0) == 0
              }
            }
            for (int q = 0; q < nc; ++q) {
              int m3 = cand[q];
              int am3 = m3 < 0 ? -m3 : m3;
              if (am3 <= lo) {
                t.ea[t.nent] = (unsigned char)(o1 + l1 + m1);
                t.eb[t.nent] = (unsigned char)(o2 + l2 + m2);
                t.ec[t.nent] = (unsigned char)(oo + lo + m3);
                t.ep[t.nent] = (unsigned char)p;
                ++t.nent;
              }
            }
          }
        ++t.npaths;
        t.pstart[t.npaths] = t.nent;
      }
  return t;
}

constexpr Tables TBL = build_tables();

// -------- flat compile-time schedule, grouped by unique (a,b) pair --------
struct Sched {
  int nent;
  unsigned char sa[512], sb[512], sc[512], sp[512];
  bool newpair[512];                // slot starts a new (a,b) product
  bool firstc[512];                 // slot is globally first touch of its c
};

constexpr Sched build_sched() {
  Sched s{};
  int pos = 0;
  bool seen[16] = {};
  for (int a = 0; a < 16; ++a)
    for (int b = 0; b < 16; ++b) {
      bool first_of_pair = true;
      for (int e = 0; e < TBL.nent; ++e) {
        if ((int)TBL.ea[e] == a && (int)TBL.eb[e] == b) {
          s.sa[pos] = (unsigned char)a;
          s.sb[pos] = (unsigned char)b;
          s.sc[pos] = TBL.ec[e];
          s.sp[pos] = TBL.ep[e];
          s.newpair[pos] = first_of_pair;
          s.firstc[pos] = !seen[TBL.ec[e]];
          seen[TBL.ec[e]] = true;
          first_of_pair = false;
          ++pos;
        }
      }
    }
  s.nent = pos;
  return s;
}

constexpr Sched SCH = build_sched();
constexpr int NENT = SCH.nent;                 // 359
constexpr int NCREG = (NENT + 63) / 64;        // 6 coef VGPRs per lane
static_assert(SCH.nent == TBL.nent, "schedule must cover all entries");
static_assert(SCH.nent <= 512, "table overflow");

// ---------------- device CG math (fp64, transcribes reference) -------------
__device__ __constant__ double FACT[11] = {
    1., 1., 2., 6., 24., 120., 720., 5040., 40320., 362880., 3628800.};

struct cplx { double re, im; };

__device__ inline double su2_cg(int j1, int m1, int j2, int m2, int j3, int m3) {
  if (m3 != m1 + m2) return 0.0;
  int vmin = -j1 + j2 + m3;
  if (-j1 + m1 > vmin) vmin = -j1 + m1;
  if (0 > vmin) vmin = 0;
  int vmax = j2 + j3 + m1;
  if (j3 - j1 + j2 < vmax) vmax = j3 - j1 + j2;
  if (j3 + m3 < vmax) vmax = j3 + m3;
  double C = (2.0 * j3 + 1.0) *
             (FACT[j3 + j1 - j2] * FACT[j3 - j1 + j2] * FACT[j1 + j2 - j3] *
              FACT[j3 + m3] * FACT[j3 - m3]) /
             (FACT[j1 + j2 + j3 + 1] * FACT[j1 - m1] * FACT[j1 + m1] *
              FACT[j2 - m2] * FACT[j2 + m2]);
  double S = 0.0;
  for (int v = vmin; v <= vmax; ++v) {
    double t = (FACT[j2 + j3 + m1 - v] * FACT[j1 - m1 + v]) /
               (FACT[v] * FACT[j3 - j1 + j2 - v] * FACT[j3 + m3 - v] *
                FACT[v + j1 - j2 - m3]);
    S += (((v + j2 + m2) & 1) ? -1.0 : 1.0) * t;
  }
  return sqrt(C) * S;
}

// q[l+m, l+-|m|] of _change_basis_real_to_complex, incl. global (-i)^l phase.
__device__ inline cplx Qmat(int l, int r, int c) {
  int m = r - l, mc = c - l;
  const double is2 = 0.70710678118654752440;
  double re = 0.0, im = 0.0;
  if (m < 0) {
    if (mc == -m) re = is2;
    else if (mc == m) im = -is2;
  } else if (m == 0) {
    if (mc == 0) re = 1.0;
  } else {
    double s = (m & 1) ? -is2 : is2;
    if (mc == m) re = s;
    else if (mc == -m) im = s;
  }
  cplx out;
  switch (l & 3) {                   // multiply by (-i)^l
    case 0: out.re = re;  out.im = im;  break;
    case 1: out.re = im;  out.im = -re; break;
    case 2: out.re = -re; out.im = -im; break;
    default: out.re = -im; out.im = re; break;
  }
  return out;
}

// One block per path. Computes real-basis CG values and writes
// weights[p]*sqrt(2lo+1)*Creal into the SCHEDULE-ORDERED coefficient slots.
__global__ void cg_setup_kernel(const float* __restrict__ weights,
                                float* __restrict__ wwc) {
  const int p = blockIdx.x;
  const int l1 = TBL.pl1[p], l2 = TBL.pl2[p], lo = TBL.plo[p];
  const int n1 = 2 * l1 + 1, n2 = 2 * l2 + 1, n3 = 2 * lo + 1;
  const int tot = n1 * n2 * n3;
  const int tid = (int)threadIdx.x;
  const int bd = (int)blockDim.x;

  __shared__ double Cs[343];
  __shared__ double Vr[343], Vi[343];
  __shared__ double Ur[343], Ui[343];
  __shared__ double Rr[343];

  // stage 0: SU(2) CG tensor Cs[i,k,n]
  for (int idx = tid; idx < tot; idx += bd) {
    int i = idx / (n2 * n3), r = idx % (n2 * n3);
    int k = r / n3, nn = r % n3;
    Cs[idx] = su2_cg(l1, i - l1, l2, k - l2, lo, nn - lo);
  }
  __syncthreads();

  // stage A: V[i,k,m] = sum_n Cs[i,k,n] * conj(Q3[n,m])
  for (int idx = tid; idx < tot; idx += bd) {
    int i = idx / (n2 * n3), r = idx % (n2 * n3);
    int k = r / n3, m = r % n3;
    double vr = 0.0, vi = 0.0;
    for (int nn = 0; nn < n3; ++nn) {
      double c = Cs[(i * n2 + k) * n3 + nn];
      cplx q = Qmat(lo, nn, m);
      vr += c * q.re;
      vi -= c * q.im;
    }
    Vr[idx] = vr; Vi[idx] = vi;
  }
  __syncthreads();

  // stage B: U[i,l,m] = sum_k Q2[k,l] * V[i,k,m]
  for (int idx = tid; idx < tot; idx += bd) {
    int i = idx / (n2 * n3), r = idx % (n2 * n3);
    int l = r / n3, m = r % n3;
    double ur = 0.0, ui = 0.0;
    for (int k = 0; k < n2; ++k) {
      cplx q = Qmat(l2, k, l);
      double vr = Vr[(i * n2 + k) * n3 + m];
      double vi = Vi[(i * n2 + k) * n3 + m];
      ur += q.re * vr - q.im * vi;
      ui += q.re * vi + q.im * vr;
    }
    Ur[idx] = ur; Ui[idx] = ui;
  }
  __syncthreads();

  // stage C: R[j,l,m] = Re( sum_i Q1[i,j] * U[i,l,m] )
  for (int idx = tid; idx < tot; idx += bd) {
    int j = idx / (n2 * n3), r = idx % (n2 * n3);
    int l = r / n3, m = r % n3;
    double rr = 0.0;
    for (int i = 0; i < n1; ++i) {
      cplx q = Qmat(l1, i, j);
      rr += q.re * Ur[(i * n2 + l) * n3 + m] - q.im * Ui[(i * n2 + l) * n3 + m];
    }
    Rr[idx] = rr;
  }
  __syncthreads();

  // write schedule-ordered coefficients belonging to this path
  const double wsc = (double)weights[p] * sqrt(2.0 * lo + 1.0);
  const int o1 = l1 * l1, o2 = l2 * l2, oo = lo * lo;
  for (int s = tid; s < NENT; s += bd) {
    if ((int)SCH.sp[s] != p) continue;
    int i = (int)SCH.sa[s] - o1;
    int j = (int)SCH.sb[s] - o2;
    int k = (int)SCH.sc[s] - oo;
    wwc[s] = (float)(wsc * Rr[(i * n2 + j) * n3 + k]);
  }
}

// ---------------- main contraction kernel (v1-proven shape + VALU diet) ----
__global__ __launch_bounds__(256) void tp_kernel(const float* __restrict__ x1,
                                                 const float* __restrict__ x2,
                                                 const float* __restrict__ wwc,
                                                 float* __restrict__ out,
                                                 int n) {
  const int lane = (int)threadIdx.x & 63;

  // coefficient stripe: lane L holds wwc[L + 64k]. Loaded before any
  // divergence so every lane's VGPRs are valid for readlane.
  float creg[NCREG];
#pragma unroll
  for (int k = 0; k < NCREG; ++k) creg[k] = wwc[k * 64 + lane];

  const int row = (int)blockIdx.x * 256 + (int)threadIdx.x;
  if (row >= n) return;

  const float4* X1 = reinterpret_cast<const float4*>(x1) + (size_t)row * 4;
  const float4* X2 = reinterpret_cast<const float4*>(x2) + (size_t)row * 4;

  float a[16], b[16];
#pragma unroll
  for (int q = 0; q < 4; ++q) {
    float4 t = X1[q];
    a[4 * q + 0] = t.x; a[4 * q + 1] = t.y; a[4 * q + 2] = t.z; a[4 * q + 3] = t.w;
    float4 u = X2[q];
    b[4 * q + 0] = u.x; b[4 * q + 1] = u.y; b[4 * q + 2] = u.z; b[4 * q + 3] = u.w;
  }

  float acc[16];                     // first-touch initialized via firstc
  float t = 0.0f;                    // current (a,b) product

#pragma unroll
  for (int e = 0; e < NENT; ++e) {
    // all SCH.* reads constant-fold after full unroll (v1/v4-proven)
    if (SCH.newpair[e]) t = a[SCH.sa[e]] * b[SCH.sb[e]];
    // wave-uniform coefficient -> SGPR via readlane (compile-time lane idx)
    int wb = __builtin_amdgcn_readlane(__float_as_int(creg[e >> 6]), e & 63);
    float w = __int_as_float(wb);
    if (SCH.firstc[e]) acc[SCH.sc[e]] = w * t;
    else               acc[SCH.sc[e]] = fmaf(w, t, acc[SCH.sc[e]]);
  }

  v4f* O = reinterpret_cast<v4f*>(out) + (size_t)row * 4;
#pragma unroll
  for (int q = 0; q < 4; ++q) {
    v4f o;
    o.x = acc[4 * q + 0]; o.y = acc[4 * q + 1];
    o.z = acc[4 * q + 2]; o.w = acc[4 * q + 3];
    O[q] = o;                        // plain store: L2 merges partial lines
  }
}

// ---------------- launch ----------------
extern "C" void kernel_launch(void* const* d_in, const int* in_sizes, int n_in,
                              void* d_out, int out_size, void* d_ws,
                              size_t ws_size, hipStream_t stream) {
  const float* x1 = (const float*)d_in[0];
  const float* x2 = (const float*)d_in[1];
  const float* w  = (const float*)d_in[2];
  float* out = (float*)d_out;
  float* wwc = (float*)d_ws;   // NENT compacted coefficients (schedule order)

  const int n = in_sizes[0] / 16;

  // 1) compute compacted ww3j coefficients (23 tiny blocks)
  cg_setup_kernel<<<dim3(TBL.npaths), dim3(256), 0, stream>>>(w, wwc);

  // 2) sparse per-row contraction (1 row/thread, proven-promotable shape)
  const int grid = (n + 255) / 256;
  tp_kernel<<<dim3(grid), dim3(256), 0, stream>>>(x1, x2, wwc, out, n);
}

// Round 9
// 831.631 us; speedup vs baseline: 1.9828x; 1.6422x over previous
//
#include <hip/hip_runtime.h>

// ============================================================================
// FilteredTensorProduct: out[n,c] = sum_{a,b} x1[n,a] x2[n,b] ww3j[a,b,c]
//   ww3j = sum_p weights[p] * W3J[p]   (23 SO(3) CG paths, lmax=3, dims 16)
//
// v8 = v1's EXACT loop body (the only one that promotes WITH readlane:
// flat unroll, no conditionals, unconditional fmaf, zero-init acc) +
// c-half accumulator split to get under the 64-VGPR occupancy cliff.
//
// Promotion ledger (hardware-measured):
//   v1: flat loop, no conditionals, readlane          -> 80 VGPR, 113us  OK
//   v4: flat loop, firstc/newpair conds, uniform load -> 72 VGPR         OK
//   v7: conds + readlane (convergent)                 -> 40 VGPR, 1243us DEMOTED
//   v2/v3/v6: 2 rows/thread (96 floats)               -> demoted, 1.4-1.8ms
//   v5: LDS staging                                   -> folded to ds_reads, 1521us
// => readlane loop must be conditional-free; footprint must stay small.
//
// v8 changes vs v1 (nothing else):
//  - entries reordered c-half-major at compile time; two scoped sections
//    each with acc[8] (zero-init, v1-style). Nominal footprint 54 -> 46.
//  - __launch_bounds__(256, 8): request 8 waves/EU -> <=64 VGPR -> 2x the
//    resident waves of v1 (which sat at 80 VGPR / 4 waves/SIMD / occ 25%,
//    latency-bound with both pipes idle).
//  - stores split 2+2 float4 (after each half's section).
// ============================================================================

typedef float v4f __attribute__((ext_vector_type(4)));

// ---------------- compile-time sparsity pattern ----------------
struct Tables {
  int npaths;
  int pl1[32], pl2[32], plo[32];
  int nent;
  int pstart[33];
  unsigned char ea[512], eb[512], ec[512], ep[512];
};

constexpr Tables build_tables() {
  Tables t{};
  for (int lo = 0; lo <= 3; ++lo)
    for (int l1 = 0; l1 <= 3; ++l1)
      for (int l2 = 0; l2 <= 3; ++l2) {
        if (((l1 + l2 + lo) & 1) != 0) continue;           // parity rule
        int lmin = l1 > l2 ? l1 - l2 : l2 - l1;
        if (lo > l1 + l2 || lo < lmin) continue;           // triangle rule
        int p = t.npaths;
        t.pl1[p] = l1; t.pl2[p] = l2; t.plo[p] = lo;
        t.pstart[p] = t.nent;
        int o1 = l1 * l1, o2 = l2 * l2, oo = lo * lo;
        for (int m1 = -l1; m1 <= l1; ++m1)
          for (int m2 = -l2; m2 <= l2; ++m2) {
            int cand[2] = {0, 0}; int nc = 0;
            if (m1 == 0) cand[nc++] = m2;                  // Y_{l,0} has no phi dep
            else if (m2 == 0) cand[nc++] = m1;
            else {
              int u = m1 < 0 ? -m1 : m1, v = m2 < 0 ? -m2 : m2;
              int d = u > v ? u - v : v - u;
              if ((m1 > 0) == (m2 > 0)) {                  // cos*cos or sin*sin -> cos
                cand[nc++] = u + v; cand[nc++] = d;
              } else {                                     // sin*cos -> sin
                cand[nc++] = -(u + v);
                if (d) cand[nc++] = -d;                    // sin(0) == 0
              }
            }
            for (int q = 0; q < nc; ++q) {
              int m3 = cand[q];
              int am3 = m3 < 0 ? -m3 : m3;
              if (am3 <= lo) {
                t.ea[t.nent] = (unsigned char)(o1 + l1 + m1);
                t.eb[t.nent] = (unsigned char)(o2 + l2 + m2);
                t.ec[t.nent] = (unsigned char)(oo + lo + m3);
                t.ep[t.nent] = (unsigned char)p;
                ++t.nent;
              }
            }
          }
        ++t.npaths;
        t.pstart[t.npaths] = t.nent;
      }
  return t;
}

constexpr Tables TBL = build_tables();

// -------- compile-time reorder: entries sorted by output half (c>>3) ------
struct Ord {
  int nent;
  int hstart[3];                    // section boundaries: [h0, h1, end]
  unsigned char ra[512], rb[512], rc[512], op[512];
};

constexpr Ord build_ord() {
  Ord o{};
  int pos = 0;
  for (int h = 0; h < 2; ++h) {
    o.hstart[h] = pos;
    for (int e = 0; e < TBL.nent; ++e) {
      if (((int)TBL.ec[e] >> 3) == h) {
        o.ra[pos] = TBL.ea[e];
        o.rb[pos] = TBL.eb[e];
        o.rc[pos] = TBL.ec[e];
        o.op[pos] = TBL.ep[e];
        ++pos;
      }
    }
  }
  o.hstart[2] = pos;
  o.nent = pos;
  return o;
}

constexpr Ord ORD = build_ord();
constexpr int NENT = ORD.nent;                 // 359
constexpr int NCREG = (NENT + 63) / 64;        // 6 coef VGPRs per lane
static_assert(ORD.nent == TBL.nent, "reorder must cover all entries");
static_assert(ORD.nent <= 512, "table overflow");

// ---------------- device CG math (fp64, transcribes reference) -------------
__device__ __constant__ double FACT[11] = {
    1., 1., 2., 6., 24., 120., 720., 5040., 40320., 362880., 3628800.};

struct cplx { double re, im; };

__device__ inline double su2_cg(int j1, int m1, int j2, int m2, int j3, int m3) {
  if (m3 != m1 + m2) return 0.0;
  int vmin = -j1 + j2 + m3;
  if (-j1 + m1 > vmin) vmin = -j1 + m1;
  if (0 > vmin) vmin = 0;
  int vmax = j2 + j3 + m1;
  if (j3 - j1 + j2 < vmax) vmax = j3 - j1 + j2;
  if (j3 + m3 < vmax) vmax = j3 + m3;
  double C = (2.0 * j3 + 1.0) *
             (FACT[j3 + j1 - j2] * FACT[j3 - j1 + j2] * FACT[j1 + j2 - j3] *
              FACT[j3 + m3] * FACT[j3 - m3]) /
             (FACT[j1 + j2 + j3 + 1] * FACT[j1 - m1] * FACT[j1 + m1] *
              FACT[j2 - m2] * FACT[j2 + m2]);
  double S = 0.0;
  for (int v = vmin; v <= vmax; ++v) {
    double t = (FACT[j2 + j3 + m1 - v] * FACT[j1 - m1 + v]) /
               (FACT[v] * FACT[j3 - j1 + j2 - v] * FACT[j3 + m3 - v] *
                FACT[v + j1 - j2 - m3]);
    S += (((v + j2 + m2) & 1) ? -1.0 : 1.0) * t;
  }
  return sqrt(C) * S;
}

// q[l+m, l+-|m|] of _change_basis_real_to_complex, incl. global (-i)^l phase.
__device__ inline cplx Qmat(int l, int r, int c) {
  int m = r - l, mc = c - l;
  const double is2 = 0.70710678118654752440;
  double re = 0.0, im = 0.0;
  if (m < 0) {
    if (mc == -m) re = is2;
    else if (mc == m) im = -is2;
  } else if (m == 0) {
    if (mc == 0) re = 1.0;
  } else {
    double s = (m & 1) ? -is2 : is2;
    if (mc == m) re = s;
    else if (mc == -m) im = s;
  }
  cplx out;
  switch (l & 3) {                   // multiply by (-i)^l
    case 0: out.re = re;  out.im = im;  break;
    case 1: out.re = im;  out.im = -re; break;
    case 2: out.re = -re; out.im = -im; break;
    default: out.re = -im; out.im = re; break;
  }
  return out;
}

// One block per path. Computes real-basis CG values and writes
// weights[p]*sqrt(2lo+1)*Creal into the ORD-ORDERED coefficient slots.
__global__ void cg_setup_kernel(const float* __restrict__ weights,
                                float* __restrict__ wwc) {
  const int p = blockIdx.x;
  const int l1 = TBL.pl1[p], l2 = TBL.pl2[p], lo = TBL.plo[p];
  const int n1 = 2 * l1 + 1, n2 = 2 * l2 + 1, n3 = 2 * lo + 1;
  const int tot = n1 * n2 * n3;
  const int tid = (int)threadIdx.x;
  const int bd = (int)blockDim.x;

  __shared__ double Cs[343];
  __shared__ double Vr[343], Vi[343];
  __shared__ double Ur[343], Ui[343];
  __shared__ double Rr[343];

  // stage 0: SU(2) CG tensor Cs[i,k,n]
  for (int idx = tid; idx < tot; idx += bd) {
    int i = idx / (n2 * n3), r = idx % (n2 * n3);
    int k = r / n3, nn = r % n3;
    Cs[idx] = su2_cg(l1, i - l1, l2, k - l2, lo, nn - lo);
  }
  __syncthreads();

  // stage A: V[i,k,m] = sum_n Cs[i,k,n] * conj(Q3[n,m])
  for (int idx = tid; idx < tot; idx += bd) {
    int i = idx / (n2 * n3), r = idx % (n2 * n3);
    int k = r / n3, m = r % n3;
    double vr = 0.0, vi = 0.0;
    for (int nn = 0; nn < n3; ++nn) {
      double c = Cs[(i * n2 + k) * n3 + nn];
      cplx q = Qmat(lo, nn, m);
      vr += c * q.re;
      vi -= c * q.im;
    }
    Vr[idx] = vr; Vi[idx] = vi;
  }
  __syncthreads();

  // stage B: U[i,l,m] = sum_k Q2[k,l] * V[i,k,m]
  for (int idx = tid; idx < tot; idx += bd) {
    int i = idx / (n2 * n3), r = idx % (n2 * n3);
    int l = r / n3, m = r % n3;
    double ur = 0.0, ui = 0.0;
    for (int k = 0; k < n2; ++k) {
      cplx q = Qmat(l2, k, l);
      double vr = Vr[(i * n2 + k) * n3 + m];
      double vi = Vi[(i * n2 + k) * n3 + m];
      ur += q.re * vr - q.im * vi;
      ui += q.re * vi + q.im * vr;
    }
    Ur[idx] = ur; Ui[idx] = ui;
  }
  __syncthreads();

  // stage C: R[j,l,m] = Re( sum_i Q1[i,j] * U[i,l,m] )
  for (int idx = tid; idx < tot; idx += bd) {
    int j = idx / (n2 * n3), r = idx % (n2 * n3);
    int l = r / n3, m = r % n3;
    double rr = 0.0;
    for (int i = 0; i < n1; ++i) {
      cplx q = Qmat(l1, i, j);
      rr += q.re * Ur[(i * n2 + l) * n3 + m] - q.im * Ui[(i * n2 + l) * n3 + m];
    }
    Rr[idx] = rr;
  }
  __syncthreads();

  // write ORD-ordered coefficients belonging to this path
  const double wsc = (double)weights[p] * sqrt(2.0 * lo + 1.0);
  const int o1 = l1 * l1, o2 = l2 * l2, oo = lo * lo;
  for (int s = tid; s < NENT; s += bd) {
    if ((int)ORD.op[s] != p) continue;
    int i = (int)ORD.ra[s] - o1;
    int j = (int)ORD.rb[s] - o2;
    int k = (int)ORD.rc[s] - oo;
    wwc[s] = (float)(wsc * Rr[(i * n2 + j) * n3 + k]);
  }
}

// ---------------- main contraction kernel ----------------
// v1 body, c-half accumulator split, 8 waves/EU requested.
__global__ __launch_bounds__(256, 8) void tp_kernel(
    const float* __restrict__ x1, const float* __restrict__ x2,
    const float* __restrict__ wwc, float* __restrict__ out, int n) {
  const int lane = (int)threadIdx.x & 63;

  // coefficient stripe: lane L holds wwc[L + 64k]. Loaded before any
  // divergence so every lane's VGPRs are valid for readlane.
  float creg[NCREG];
#pragma unroll
  for (int k = 0; k < NCREG; ++k) creg[k] = wwc[k * 64 + lane];

  const int row = (int)blockIdx.x * 256 + (int)threadIdx.x;
  if (row >= n) return;

  const float4* X1 = reinterpret_cast<const float4*>(x1) + (size_t)row * 4;
  const float4* X2 = reinterpret_cast<const float4*>(x2) + (size_t)row * 4;

  float a[16], b[16];
#pragma unroll
  for (int q = 0; q < 4; ++q) {
    float4 t = X1[q];
    a[4 * q + 0] = t.x; a[4 * q + 1] = t.y; a[4 * q + 2] = t.z; a[4 * q + 3] = t.w;
    float4 u = X2[q];
    b[4 * q + 0] = u.x; b[4 * q + 1] = u.y; b[4 * q + 2] = u.z; b[4 * q + 3] = u.w;
  }

  float4* O = reinterpret_cast<float4*>(out) + (size_t)row * 4;

  // ---- section 0: outputs c = 0..7 ----
  {
    float acc[8];
#pragma unroll
    for (int c = 0; c < 8; ++c) acc[c] = 0.0f;
#pragma unroll
    for (int e = 0; e < ORD.hstart[1]; ++e) {
      // v1-proven body: no conditionals, constant indices, readlane
      int wb = __builtin_amdgcn_readlane(__float_as_int(creg[e >> 6]), e & 63);
      float w = __int_as_float(wb);
      acc[(int)ORD.rc[e] & 7] =
          fmaf(w, a[ORD.ra[e]] * b[ORD.rb[e]], acc[(int)ORD.rc[e] & 7]);
    }
    O[0] = make_float4(acc[0], acc[1], acc[2], acc[3]);
    O[1] = make_float4(acc[4], acc[5], acc[6], acc[7]);
  }

  // ---- section 1: outputs c = 8..15 ----
  {
    float acc[8];
#pragma unroll
    for (int c = 0; c < 8; ++c) acc[c] = 0.0f;
#pragma unroll
    for (int e = ORD.hstart[1]; e < NENT; ++e) {
      int wb = __builtin_amdgcn_readlane(__float_as_int(creg[e >> 6]), e & 63);
      float w = __int_as_float(wb);
      acc[(int)ORD.rc[e] & 7] =
          fmaf(w, a[ORD.ra[e]] * b[ORD.rb[e]], acc[(int)ORD.rc[e] & 7]);
    }
    O[2] = make_float4(acc[0], acc[1], acc[2], acc[3]);
    O[3] = make_float4(acc[4], acc[5], acc[6], acc[7]);
  }
}

// ---------------- launch ----------------
extern "C" void kernel_launch(void* const* d_in, const int* in_sizes, int n_in,
                              void* d_out, int out_size, void* d_ws,
                              size_t ws_size, hipStream_t stream) {
  const float* x1 = (const float*)d_in[0];
  const float* x2 = (const float*)d_in[1];
  const float* w  = (const float*)d_in[2];
  float* out = (float*)d_out;
  float* wwc = (float*)d_ws;   // NENT compacted coefficients (ORD order)

  const int n = in_sizes[0] / 16;

  // 1) compute compacted ww3j coefficients (23 tiny blocks)
  cg_setup_kernel<<<dim3(TBL.npaths), dim3(256), 0, stream>>>(w, wwc);

  // 2) sparse per-row contraction (1 row/thread, v1 body, acc split)
  const int grid = (n + 255) / 256;
  tp_kernel<<<dim3(grid), dim3(256), 0, stream>>>(x1, x2, wwc, out, n);
}